// Round 1
// baseline (1431.089 us; speedup 1.0000x reference)
//
#include <hip/hip_runtime.h>
#include <stdint.h>

#define N_ANCH 193536
#define BATCH  16
#define NCLS   9
#define NBC    (BATCH * NCLS)   // 144
#define TOPK   1000
#define CAP    2048
#define EQCAP  (CAP - TOPK)     // 1048 slots for ==pivot candidates
#define MAXDET 100
#define KOFF   0x3C800000u      // 121 << 23; scores in (0.05,1) -> key in (0, 2^26)

// ---------- exact-arith helpers (mirror reference op order; no FMA contraction) ----

__device__ __forceinline__ float sigm(float x) {
#pragma clang fp contract(off)
    return 1.0f / (1.0f + expf(-x));
}

__device__ __forceinline__ uint32_t score_key(float s) {
    // masked = where(s > 0.05, s, -1); only s>0.05 can enter top-k in practice
    return (s > 0.05f) ? (__float_as_uint(s) - KOFF) : 0u;
}

__device__ __forceinline__ void decode_box(const float* __restrict__ a,
                                           const float* __restrict__ d,
                                           float* bx) {
#pragma clang fp contract(off)
    float a0 = a[0], a1 = a[1], a2 = a[2], a3 = a[3];
    float acx = (a0 + a2) * 0.5f;            // == (a0+a2)/2 bitwise
    float acy = (a1 + a3) * 0.5f;
    float aw  = fmaxf(a2 - a0, 1.0f);
    float ah  = fmaxf(a3 - a1, 1.0f);
    float cx  = d[0] * aw + acx;             // mul then add (contract off)
    float cy  = d[1] * ah + acy;
    // exp in double then round -> correctly-rounded f32 exp (closest to CPU ref)
    float w = (float)exp((double)fminf(d[2], 4.0f)) * aw;
    float h = (float)exp((double)fminf(d[3], 4.0f)) * ah;
    bx[0] = cx - w * 0.5f;
    bx[1] = cy - h * 0.5f;
    bx[2] = cx + w * 0.5f;
    bx[3] = cy + h * 0.5f;
}

// ---------- kernel 1: per-(b,c) exact top-1000 (radix select + bitonic) ----------

__global__ __launch_bounds__(1024) void select_kernel(
    const float* __restrict__ anchors, const float* __restrict__ deltas,
    const float* __restrict__ cls,     const float* __restrict__ obj,
    uint64_t* __restrict__ cand,       // [NBC][CAP]
    float* __restrict__ sel_box,       // [NBC][TOPK][4]
    float* __restrict__ sel_score)     // [NBC][TOPK]
{
    __shared__ __align__(16) uint32_t hist[8192];   // also reused as u64 sort buf (16KB of 32KB)
    __shared__ uint32_t chunk[1024];
    __shared__ uint32_t sh_d1, sh_G1, sh_pivot, sh_G1G2;
    __shared__ uint32_t cntG, cntE;

    const int blk = blockIdx.x;
    const int b = blk / NCLS, c = blk % NCLS;
    const int tid = threadIdx.x;
    const float* clsb = cls + (size_t)b * N_ANCH * NCLS + c;
    const float* objb = obj + (size_t)b * N_ANCH;

    // ---- pass A: histogram of high 13 bits ----
    for (int i = tid; i < 8192; i += 1024) hist[i] = 0;
    __syncthreads();
    for (int n = tid; n < N_ANCH; n += 1024) {
        float s = sigm(clsb[(size_t)n * NCLS]) * sigm(objb[n]);
        uint32_t k = score_key(s);
        atomicAdd(&hist[k >> 13], 1u);
    }
    __syncthreads();
    { uint32_t csum = 0;
      for (int j = 0; j < 8; ++j) csum += hist[tid * 8 + j];
      chunk[tid] = csum; }
    __syncthreads();
    if (tid == 0) {
        uint32_t cum = 0, d1 = 0, g1 = 0;
        for (int t = 1023; t >= 0; --t) {
            if (cum + chunk[t] >= TOPK) {
                for (int j = 7; j >= 0; --j) {
                    uint32_t h = hist[t * 8 + j];
                    if (cum + h >= TOPK) { d1 = (uint32_t)(t * 8 + j); g1 = cum; goto doneA; }
                    cum += h;
                }
            }
            cum += chunk[t];
        }
doneA:  sh_d1 = d1; sh_G1 = g1;
    }
    __syncthreads();
    const uint32_t d1 = sh_d1, G1 = sh_G1;

    // ---- pass B: histogram of low 13 bits within digit d1 ----
    for (int i = tid; i < 8192; i += 1024) hist[i] = 0;
    __syncthreads();
    for (int n = tid; n < N_ANCH; n += 1024) {
        float s = sigm(clsb[(size_t)n * NCLS]) * sigm(objb[n]);
        uint32_t k = score_key(s);
        if ((k >> 13) == d1) atomicAdd(&hist[k & 8191u], 1u);
    }
    __syncthreads();
    { uint32_t csum = 0;
      for (int j = 0; j < 8; ++j) csum += hist[tid * 8 + j];
      chunk[tid] = csum; }
    __syncthreads();
    if (tid == 0) {
        const uint32_t K2 = TOPK - G1;    // >= 1
        uint32_t cum = 0, d2 = 0, g2 = 0;
        for (int t = 1023; t >= 0; --t) {
            if (cum + chunk[t] >= K2) {
                for (int j = 7; j >= 0; --j) {
                    uint32_t h = hist[t * 8 + j];
                    if (cum + h >= K2) { d2 = (uint32_t)(t * 8 + j); g2 = cum; goto doneB; }
                    cum += h;
                }
            }
            cum += chunk[t];
        }
doneB:  sh_pivot = (d1 << 13) | d2;
        sh_G1G2 = G1 + g2;                 // count of keys strictly > pivot, < TOPK
        cntG = 0; cntE = 0;
    }
    __syncthreads();
    const uint32_t pivot = sh_pivot;

    // ---- pass C: compact (>pivot) and (==pivot) candidates to global ----
    uint64_t* mycand = cand + (size_t)blk * CAP;
    for (int n = tid; n < N_ANCH; n += 1024) {
        float s = sigm(clsb[(size_t)n * NCLS]) * sigm(objb[n]);
        uint32_t k = score_key(s);
        if (k != 0 && k >= pivot) {
            uint64_t e = ((uint64_t)k << 32) | (uint64_t)(0xFFFFFFFFu - (uint32_t)n);
            if (k > pivot) {
                uint32_t p = atomicAdd(&cntG, 1u);
                mycand[p] = e;                       // p < TOPK guaranteed
            } else {
                uint32_t p = atomicAdd(&cntE, 1u);
                if (p < EQCAP) mycand[TOPK + p] = e; // ties: sort picks smallest idx
            }
        }
    }
    __threadfence();          // make global writes visible to own block's reads
    __syncthreads();

    // ---- sort candidates: u64 desc == (score desc, idx asc) ----
    const uint32_t G = cntG;
    const uint32_t E = min(cntE, (uint32_t)EQCAP);
    uint64_t* sbuf = (uint64_t*)hist;
    for (int i = tid; i < CAP; i += 1024) {
        uint64_t e = 0;
        if ((uint32_t)i < G) e = mycand[i];
        else if ((uint32_t)i < G + E) e = mycand[TOPK + (i - G)];
        sbuf[i] = e;
    }
    __syncthreads();
    for (int k = 2; k <= CAP; k <<= 1) {
        for (int j = k >> 1; j > 0; j >>= 1) {
            for (int i = tid; i < CAP; i += 1024) {
                int ixj = i ^ j;
                if (ixj > i) {
                    uint64_t va = sbuf[i], vb = sbuf[ixj];
                    bool up = ((i & k) == 0);          // descending overall
                    if (up ? (va < vb) : (va > vb)) { sbuf[i] = vb; sbuf[ixj] = va; }
                }
            }
            __syncthreads();
        }
    }

    // ---- emit top-1000: score + decoded box ----
    for (int t = tid; t < TOPK; t += 1024) {
        uint64_t e = sbuf[t];
        uint32_t k = (uint32_t)(e >> 32);
        float bx[4] = {0.f, 0.f, 0.f, 0.f};
        float score = 0.f;
        if (k != 0) {
            uint32_t idx = 0xFFFFFFFFu - (uint32_t)(e & 0xFFFFFFFFu);
            score = __uint_as_float(k + KOFF);
            decode_box(anchors + (size_t)idx * 4,
                       deltas + ((size_t)b * N_ANCH + idx) * 4, bx);
        }
        sel_score[(size_t)blk * TOPK + t] = score;
        float* o = sel_box + ((size_t)blk * TOPK + t) * 4;
        o[0] = bx[0]; o[1] = bx[1]; o[2] = bx[2]; o[3] = bx[3];
    }
}

// ---------- kernel 2: greedy NMS (sequential, barrier loop; exact) ----------

__global__ __launch_bounds__(1024) void nms_kernel(
    const float* __restrict__ sel_box, const float* __restrict__ sel_score,
    float* __restrict__ final_score)   // [NBC][TOPK]
{
    __shared__ float bx0[TOPK], by0[TOPK], bx1[TOPK], by1[TOPK], barea[TOPK];
    __shared__ uint8_t keep[TOPK];
    const int blk = blockIdx.x;
    const int tid = threadIdx.x;

    for (int t = tid; t < TOPK; t += 1024) {
#pragma clang fp contract(off)
        const float* p = sel_box + ((size_t)blk * TOPK + t) * 4;
        float x0 = p[0], y0 = p[1], x1 = p[2], y1 = p[3];
        bx0[t] = x0; by0[t] = y0; bx1[t] = x1; by1[t] = y1;
        barea[t] = (x1 - x0) * (y1 - y0);   // ref area op order
        keep[t] = 1;
    }
    __syncthreads();

    const int j = tid;
    bool alive = (j < TOPK);
    float jx0 = 0, jy0 = 0, jx1 = 0, jy1 = 0, ja = 0;
    if (alive) { jx0 = bx0[j]; jy0 = by0[j]; jx1 = bx1[j]; jy1 = by1[j]; ja = barea[j]; }

    for (int i = 0; i < TOPK - 1; ++i) {
        if (keep[i]) {                      // uniform branch (same LDS word)
            if (alive && j > i) {
#pragma clang fp contract(off)
                float xx0 = fmaxf(bx0[i], jx0);
                float yy0 = fmaxf(by0[i], jy0);
                float xx1 = fminf(bx1[i], jx1);
                float yy1 = fminf(by1[i], jy1);
                float iw = fmaxf(xx1 - xx0, 0.0f);
                float ih = fmaxf(yy1 - yy0, 0.0f);
                float inter = iw * ih;
                float uni = fmaxf((barea[i] + ja) - inter, 1e-6f); // a1+a2-inter, clip
                float iou = inter / uni;                            // real division (ref)
                if (iou > 0.5f) { keep[j] = 0; alive = false; }
            }
        }
        __syncthreads();
    }

    for (int t = tid; t < TOPK; t += 1024) {
        float s = sel_score[(size_t)blk * TOPK + t];
        float v = (keep[t] && (s > 0.05f)) ? s : 0.0f;   // valid = keep & vals>thresh
        final_score[(size_t)blk * TOPK + t] = v;
    }
}

// ---------- kernel 3: per-image top-100 (repeated argmax, index tie-break) ------

__global__ __launch_bounds__(1024) void final_kernel(
    const float* __restrict__ final_score, const float* __restrict__ sel_box,
    float* __restrict__ out)   // [BATCH][MAXDET][6]
{
    __shared__ float s[NCLS * TOPK];       // 36 KB
    __shared__ float wv[16];
    __shared__ int   wi[16];
    const int b = blockIdx.x;
    const int tid = threadIdx.x;
    const int lane = tid & 63, wave = tid >> 6;

    for (int t = tid; t < NCLS * TOPK; t += 1024)
        s[t] = final_score[(size_t)b * NCLS * TOPK + t];
    __syncthreads();

    for (int r = 0; r < MAXDET; ++r) {
        float bv = -1.0f; int bi = 0x7FFFFFFF;
        for (int t = tid; t < NCLS * TOPK; t += 1024) {
            float v = s[t];
            if (v > bv || (v == bv && t < bi)) { bv = v; bi = t; }
        }
        for (int off = 32; off > 0; off >>= 1) {
            float ov = __shfl_down(bv, off);
            int   oi = __shfl_down(bi, off);
            if (ov > bv || (ov == bv && oi < bi)) { bv = ov; bi = oi; }
        }
        if (lane == 0) { wv[wave] = bv; wi[wave] = bi; }
        __syncthreads();
        if (tid == 0) {
            float fbv = wv[0]; int fbi = wi[0];
            for (int k = 1; k < 16; ++k)
                if (wv[k] > fbv || (wv[k] == fbv && wi[k] < fbi)) { fbv = wv[k]; fbi = wi[k]; }
            s[fbi] = -2.0f;   // remove; zeros stay pickable (matches top_k distinct picks)
            const float* bxp = sel_box + ((size_t)b * NCLS * TOPK + fbi) * 4;
            float* o = out + ((size_t)b * MAXDET + r) * 6;
            o[0] = bxp[0]; o[1] = bxp[1]; o[2] = bxp[2]; o[3] = bxp[3];
            o[4] = fbv;    o[5] = (float)(fbi / TOPK);
        }
        __syncthreads();
    }
}

// ---------------------------------- launcher -----------------------------------

extern "C" void kernel_launch(void* const* d_in, const int* in_sizes, int n_in,
                              void* d_out, int out_size, void* d_ws, size_t ws_size,
                              hipStream_t stream) {
    const float* anchors = (const float*)d_in[0];
    const float* deltas  = (const float*)d_in[1];
    const float* cls     = (const float*)d_in[2];
    const float* obj     = (const float*)d_in[3];
    float* out = (float*)d_out;

    char* ws = (char*)d_ws;
    uint64_t* cand      = (uint64_t*)ws;                          // 144*2048*8  = 2.36 MB
    float*    sel_box   = (float*)(ws + (size_t)NBC * CAP * 8);   // 144*1000*16 = 2.30 MB
    float*    sel_score = sel_box + (size_t)NBC * TOPK * 4;       // 0.58 MB
    float*    final_sc  = sel_score + (size_t)NBC * TOPK;         // 0.58 MB

    select_kernel<<<dim3(NBC), dim3(1024), 0, stream>>>(anchors, deltas, cls, obj,
                                                        cand, sel_box, sel_score);
    nms_kernel<<<dim3(NBC), dim3(1024), 0, stream>>>(sel_box, sel_score, final_sc);
    final_kernel<<<dim3(BATCH), dim3(1024), 0, stream>>>(final_sc, sel_box, out);
}

// Round 2
// 924.394 us; speedup vs baseline: 1.5481x; 1.5481x over previous
//
#include <hip/hip_runtime.h>
#include <stdint.h>

#define N_ANCH 193536
#define BATCH  16
#define NCLS   9
#define NBC    (BATCH * NCLS)   // 144
#define TOPK   1000
#define CAP    4096             // per-(b,c) candidate capacity
#define SCAP   4096             // per-image final candidate capacity
#define MAXDET 100
#define KOFF   0x3C800000u      // 121 << 23; scores in (0.05,1) -> key in (0, 2^26)
#define HBINS  256
#define HSHIFT 18               // key >> 18 -> bin (valid keys land in bins 51..255)
#define CHUNK  8064             // N_ANCH / 24
#define BLK_PER_IMG 24
#define NMS_SUB 8
#define ROWS_PER_SUB 125        // TOPK / 8
#define NWORDS 16               // 1024 bits per mask row

// ---------- exact-arith helpers (mirror reference op order; no FMA contraction) ----

__device__ __forceinline__ float sigm(float x) {
#pragma clang fp contract(off)
    return 1.0f / (1.0f + expf(-x));
}

__device__ __forceinline__ uint32_t score_key(float s) {
    return (s > 0.05f) ? (__float_as_uint(s) - KOFF) : 0u;
}

__device__ __forceinline__ void decode_box(const float* __restrict__ a,
                                           const float* __restrict__ d,
                                           float* bx) {
#pragma clang fp contract(off)
    float a0 = a[0], a1 = a[1], a2 = a[2], a3 = a[3];
    float acx = (a0 + a2) * 0.5f;
    float acy = (a1 + a3) * 0.5f;
    float aw  = fmaxf(a2 - a0, 1.0f);
    float ah  = fmaxf(a3 - a1, 1.0f);
    float cx  = d[0] * aw + acx;
    float cy  = d[1] * ah + acy;
    float w = (float)exp((double)fminf(d[2], 4.0f)) * aw;
    float h = (float)exp((double)fminf(d[3], 4.0f)) * ah;
    bx[0] = cx - w * 0.5f;
    bx[1] = cy - h * 0.5f;
    bx[2] = cx + w * 0.5f;
    bx[3] = cy + h * 0.5f;
}

__device__ __forceinline__ void bitonic_desc(uint64_t* buf, int n, int tid, int nthr) {
    for (int k = 2; k <= n; k <<= 1) {
        for (int j = k >> 1; j > 0; j >>= 1) {
            for (int i = tid; i < n; i += nthr) {
                int ixj = i ^ j;
                if (ixj > i) {
                    uint64_t va = buf[i], vb = buf[ixj];
                    bool up = ((i & k) == 0);          // descending overall
                    if (up ? (va < vb) : (va > vb)) { buf[i] = vb; buf[ixj] = va; }
                }
            }
            __syncthreads();
        }
    }
}

// ---------- K1: coalesced score stream -> per-(b,c) 256-bin key histograms --------

__global__ __launch_bounds__(1024) void score_hist_kernel(
    const float* __restrict__ cls, const float* __restrict__ obj,
    uint32_t* __restrict__ ghist)           // [NBC][HBINS], pre-zeroed
{
    __shared__ uint32_t h[NCLS * HBINS];    // 9 KB
    const int blk = blockIdx.x, tid = threadIdx.x;
    const int b = blk / BLK_PER_IMG;
    const int start = (blk % BLK_PER_IMG) * CHUNK;

    for (int i = tid; i < NCLS * HBINS; i += 1024) h[i] = 0;
    __syncthreads();

    for (int it = 0; it < 8; ++it) {
        int off = it * 1024 + tid;
        if (off < CHUNK) {
            int n = start + off;
            float ob = sigm(obj[(size_t)b * N_ANCH + n]);
            const float* cp = cls + ((size_t)b * N_ANCH + n) * NCLS;
            #pragma unroll
            for (int c = 0; c < NCLS; ++c) {
                float s = sigm(cp[c]) * ob;
                uint32_t k = score_key(s);
                if (k) atomicAdd(&h[c * HBINS + (k >> HSHIFT)], 1u);
            }
        }
    }
    __syncthreads();
    for (int i = tid; i < NCLS * HBINS; i += 1024) {
        uint32_t v = h[i];
        if (v) atomicAdd(&ghist[(size_t)b * NCLS * HBINS + i], v);
    }
}

// ---------- K2: per-(b,c) pivot bin from histogram (one wave per block) -----------

__global__ __launch_bounds__(64) void pivot_kernel(
    const uint32_t* __restrict__ ghist, uint32_t* __restrict__ pivot,
    uint32_t* __restrict__ gcnt)
{
    const int blk = blockIdx.x;
    const int lane = threadIdx.x;
    const uint32_t* h = ghist + (size_t)blk * HBINS;
    uint32_t h0 = h[lane * 4 + 0], h1 = h[lane * 4 + 1];
    uint32_t h2 = h[lane * 4 + 2], h3 = h[lane * 4 + 3];
    uint32_t s = h0 + h1 + h2 + h3;
    uint32_t suf = s;                          // suffix-inclusive: sum over lanes >= lane
    for (int off = 1; off < 64; off <<= 1) {
        uint32_t o = __shfl_down(suf, off);
        if (lane + off < 64) suf += o;
    }
    uint32_t sufNext = __shfl_down(suf, 1);    // S(4l+4)
    if (lane == 63) sufNext = 0;
    // S(t) = count of keys with bin >= t; crossing: S(t) >= TOPK > S(t+1)
    uint32_t S3 = sufNext + h3;
    uint32_t S2 = S3 + h2;
    uint32_t S1 = S2 + h1;
    int d = -1;
    if      (S3 >= TOPK && sufNext < TOPK) d = 4 * lane + 3;
    else if (S2 >= TOPK && S3      < TOPK) d = 4 * lane + 2;
    else if (S1 >= TOPK && S2      < TOPK) d = 4 * lane + 1;
    else if (suf >= TOPK && S1     < TOPK) d = 4 * lane + 0;
    if (d >= 0) pivot[blk] = (uint32_t)d;
    if (lane == 0) {
        gcnt[blk] = 0;
        if (suf < TOPK) pivot[blk] = 0;        // fewer than TOPK valid keys: take all
    }
}

// ---------- K3: coalesced re-stream -> compact candidates >= pivot bin ------------

__global__ __launch_bounds__(1024) void compact_kernel(
    const float* __restrict__ cls, const float* __restrict__ obj,
    const uint32_t* __restrict__ pivot, uint32_t* __restrict__ gcnt,
    uint64_t* __restrict__ cand)            // [NBC][CAP]
{
    __shared__ uint32_t piv[NCLS];
    const int blk = blockIdx.x, tid = threadIdx.x;
    const int b = blk / BLK_PER_IMG;
    const int start = (blk % BLK_PER_IMG) * CHUNK;
    if (tid < NCLS) piv[tid] = pivot[b * NCLS + tid];
    __syncthreads();

    for (int it = 0; it < 8; ++it) {
        int off = it * 1024 + tid;
        if (off < CHUNK) {
            int n = start + off;
            float ob = sigm(obj[(size_t)b * N_ANCH + n]);
            const float* cp = cls + ((size_t)b * N_ANCH + n) * NCLS;
            #pragma unroll
            for (int c = 0; c < NCLS; ++c) {
                float s = sigm(cp[c]) * ob;
                uint32_t k = score_key(s);
                if (k && (k >> HSHIFT) >= piv[c]) {
                    int bc = b * NCLS + c;
                    uint32_t slot = atomicAdd(&gcnt[bc], 1u);
                    if (slot < CAP)
                        cand[(size_t)bc * CAP + slot] =
                            ((uint64_t)k << 32) | (uint64_t)(0xFFFFFFFFu - (uint32_t)n);
                }
            }
        }
    }
}

// ---------- K4: per-(b,c) sort candidates, emit top-1000 + decoded boxes ----------

__global__ __launch_bounds__(1024) void sort_emit_kernel(
    const uint64_t* __restrict__ cand, const uint32_t* __restrict__ gcnt,
    const float* __restrict__ anchors, const float* __restrict__ deltas,
    float* __restrict__ sel_box, float* __restrict__ sel_score)
{
    __shared__ uint64_t sbuf[CAP];          // 32 KB
    const int blk = blockIdx.x, tid = threadIdx.x;
    const int b = blk / NCLS;
    const uint32_t cnt = min(gcnt[blk], (uint32_t)CAP);
    for (int i = tid; i < CAP; i += 1024)
        sbuf[i] = ((uint32_t)i < cnt) ? cand[(size_t)blk * CAP + i] : 0ull;
    __syncthreads();
    bitonic_desc(sbuf, CAP, tid, 1024);
    if (tid < TOPK) {
        uint64_t e = sbuf[tid];
        uint32_t k = (uint32_t)(e >> 32);
        float bx[4] = {0.f, 0.f, 0.f, 0.f};
        float score = 0.f;
        if (k) {
            uint32_t idx = 0xFFFFFFFFu - (uint32_t)(e & 0xFFFFFFFFu);
            score = __uint_as_float(k + KOFF);
            decode_box(anchors + (size_t)idx * 4,
                       deltas + ((size_t)b * N_ANCH + idx) * 4, bx);
        }
        sel_score[(size_t)blk * TOPK + tid] = score;
        float* o = sel_box + ((size_t)blk * TOPK + tid) * 4;
        o[0] = bx[0]; o[1] = bx[1]; o[2] = bx[2]; o[3] = bx[3];
    }
}

// ---------- K5: suppression bitmask build (8 blocks per (b,c), whole-GPU) ---------
// bit-exact div-free compare: fl32(inter/uni) > 0.5f  <=>  inter > (0.5+2^-25)*uni
// (exact in double: 25-bit * 24-bit product fits 53-bit mantissa)

__global__ __launch_bounds__(1024) void mask_build_kernel(
    const float* __restrict__ sel_box, uint64_t* __restrict__ gmask)
{
    __shared__ float X0[1024], Y0[1024], X1[1024], Y1[1024], AR[1024];
    const int blk = blockIdx.x, tid = threadIdx.x;
    const int bc = blk >> 3, sub = blk & 7;
    const int lane = tid & 63, w = tid >> 6;
    {
        float x0 = 0, y0 = 0, x1 = 0, y1 = 0, a = 0;
        if (tid < TOPK) {
#pragma clang fp contract(off)
            const float* p = sel_box + ((size_t)bc * TOPK + tid) * 4;
            x0 = p[0]; y0 = p[1]; x1 = p[2]; y1 = p[3];
            a = (x1 - x0) * (y1 - y0);
        }
        X0[tid] = x0; Y0[tid] = y0; X1[tid] = x1; Y1[tid] = y1; AR[tid] = a;
    }
    __syncthreads();

    for (int r = sub * ROWS_PER_SUB + w; r < (sub + 1) * ROWS_PER_SUB; r += 16) {
        float rx0 = X0[r], ry0 = Y0[r], rx1 = X1[r], ry1 = Y1[r], ra = AR[r];
        int wf = r >> 6;
        uint64_t* rowp = gmask + ((size_t)bc * TOPK + r) * NWORDS;
        for (int ww = 0; ww < wf; ++ww)
            if (lane == 0) rowp[ww] = 0;                  // j <= r region: no suppression
        for (int ww = wf; ww < NWORDS; ++ww) {
            int j = ww * 64 + lane;
            bool pred = false;
            if (j > r && j < TOPK) {
#pragma clang fp contract(off)
                float xx0 = fmaxf(rx0, X0[j]);
                float yy0 = fmaxf(ry0, Y0[j]);
                float xx1 = fminf(rx1, X1[j]);
                float yy1 = fminf(ry1, Y1[j]);
                float iw = fmaxf(xx1 - xx0, 0.0f);
                float ih = fmaxf(yy1 - yy0, 0.0f);
                float inter = iw * ih;
                float uni = fmaxf((ra + AR[j]) - inter, 1e-6f);
                pred = ((double)inter > 0x1.000001p-1 * (double)uni);
            }
            uint64_t m = __ballot(pred);
            if (lane == 0) rowp[ww] = m;
        }
    }
}

// ---------- K6: greedy scan over bitmask (stage to LDS, one wave, ring prefetch) --

__global__ __launch_bounds__(1024) void greedy_kernel(
    const uint64_t* __restrict__ gmask, const float* __restrict__ sel_score,
    float* __restrict__ final_score)
{
    __shared__ uint64_t lmask[TOPK * NWORDS];   // 125 KB
    __shared__ uint64_t remOut[NWORDS];
    const int blk = blockIdx.x, tid = threadIdx.x;
    for (int i = tid; i < TOPK * NWORDS; i += 1024)
        lmask[i] = gmask[(size_t)blk * TOPK * NWORDS + i];
    __syncthreads();

    if (tid < 64) {
        const int lane = tid;
        uint64_t rem = 0;                 // lane w < 16 owns removed-word w
        uint64_t ring[16];
        #pragma unroll
        for (int u = 0; u < 16; ++u)
            ring[u] = (lane < NWORDS) ? lmask[u * NWORDS + lane] : 0;
        for (int ib = 0; ib < TOPK; ib += 16) {
            #pragma unroll
            for (int u = 0; u < 16; ++u) {
                int i = ib + u;
                if (i < TOPK) {
                    uint64_t row = ring[u];
                    int ipf = i + 16;     // prefetch 16 rows ahead
                    ring[u] = (lane < NWORDS && ipf < TOPK) ? lmask[ipf * NWORDS + lane] : 0;
                    int wi = i >> 6;
                    uint32_t lo = (uint32_t)__builtin_amdgcn_readlane((int)(uint32_t)rem, wi);
                    uint32_t hi = (uint32_t)__builtin_amdgcn_readlane((int)(uint32_t)(rem >> 32), wi);
                    uint64_t wv = ((uint64_t)hi << 32) | lo;
                    if (!((wv >> (i & 63)) & 1ull)) rem |= row;   // i kept: apply its row
                }
            }
        }
        if (lane < NWORDS) remOut[lane] = rem;
    }
    __syncthreads();

    if (tid < TOPK) {
        bool kept = !((remOut[tid >> 6] >> (tid & 63)) & 1ull);
        float s = sel_score[(size_t)blk * TOPK + tid];
        final_score[(size_t)blk * TOPK + tid] = (kept && s > 0.05f) ? s : 0.0f;
    }
}

// ---------- K7: per-image top-100 (hist-select + bitonic; exact tie semantics) ----

__global__ __launch_bounds__(1024) void final_kernel(
    const float* __restrict__ final_score, const float* __restrict__ sel_box,
    float* __restrict__ out)                // [BATCH][MAXDET][6]
{
    __shared__ float sc[NCLS * TOPK];       // 36 KB
    __shared__ uint32_t h[4096];            // 16 KB (score_bits >> 18)
    __shared__ uint32_t chunk[1024];
    __shared__ uint64_t sbuf[SCAP];         // 32 KB
    __shared__ int sh_d, sh_fb;
    __shared__ uint32_t cnt;
    const int b = blockIdx.x, tid = threadIdx.x;

    for (int i = tid; i < 4096; i += 1024) h[i] = 0;
    for (int t = tid; t < NCLS * TOPK; t += 1024)
        sc[t] = final_score[(size_t)b * NCLS * TOPK + t];
    if (tid == 0) cnt = 0;
    __syncthreads();

    for (int t = tid; t < NCLS * TOPK; t += 1024) {
        uint32_t bits = __float_as_uint(sc[t]);
        if (bits) atomicAdd(&h[bits >> HSHIFT], 1u);
    }
    __syncthreads();
    chunk[tid] = h[tid * 4] + h[tid * 4 + 1] + h[tid * 4 + 2] + h[tid * 4 + 3];
    __syncthreads();
    if (tid == 0) {
        int d = -1; uint32_t cum = 0;
        for (int t = 1023; t >= 0; --t) {
            if (cum + chunk[t] >= MAXDET) {
                for (int j = 3; j >= 0; --j) {
                    uint32_t v = h[t * 4 + j];
                    if (cum + v >= MAXDET) { d = t * 4 + j; goto found; }
                    cum += v;
                }
            }
            cum += chunk[t];
        }
found:
        if (d < 0) { sh_d = 0; sh_fb = 1; }   // fewer than 100 positives in image
        else       { sh_d = d; sh_fb = 0; }
    }
    __syncthreads();
    const int d = sh_d, fb = sh_fb;

    for (int t = tid; t < NCLS * TOPK; t += 1024) {
        uint32_t bits = __float_as_uint(sc[t]);
        bool take = fb ? (bits != 0 || t < 1024)                       // zeros by idx asc
                       : (bits != 0 && (bits >> HSHIFT) >= (uint32_t)d);
        if (take) {
            uint32_t slot = atomicAdd(&cnt, 1u);
            if (slot < SCAP)
                sbuf[slot] = ((uint64_t)bits << 32) | (uint64_t)(0xFFFFFFFFu - (uint32_t)t);
        }
    }
    __syncthreads();
    uint32_t c2 = min(cnt, (uint32_t)SCAP);
    for (int i = tid; i < SCAP; i += 1024)
        if ((uint32_t)i >= c2) sbuf[i] = 0;
    __syncthreads();
    bitonic_desc(sbuf, SCAP, tid, 1024);

    if (tid < MAXDET) {
        uint64_t e = sbuf[tid];
        uint32_t bits = (uint32_t)(e >> 32);
        uint32_t flat = 0xFFFFFFFFu - (uint32_t)(e & 0xFFFFFFFFu);
        float bx[4] = {0.f, 0.f, 0.f, 0.f};
        float sval = 0.f, lab = 0.f;
        if (flat < NCLS * TOPK) {
            const float* bp = sel_box + ((size_t)b * NCLS * TOPK + flat) * 4;
            bx[0] = bp[0]; bx[1] = bp[1]; bx[2] = bp[2]; bx[3] = bp[3];
            sval = __uint_as_float(bits);
            lab = (float)(flat / TOPK);
        }
        float* o = out + ((size_t)b * MAXDET + tid) * 6;
        o[0] = bx[0]; o[1] = bx[1]; o[2] = bx[2]; o[3] = bx[3];
        o[4] = sval;  o[5] = lab;
    }
}

// ---------------------------------- launcher -----------------------------------

extern "C" void kernel_launch(void* const* d_in, const int* in_sizes, int n_in,
                              void* d_out, int out_size, void* d_ws, size_t ws_size,
                              hipStream_t stream) {
    const float* anchors = (const float*)d_in[0];
    const float* deltas  = (const float*)d_in[1];
    const float* cls     = (const float*)d_in[2];
    const float* obj     = (const float*)d_in[3];
    float* out = (float*)d_out;

    // workspace layout (22.04 MB). gmask overlays cand (disjoint lifetimes).
    char* ws = (char*)d_ws;
    const size_t GMASK_BYTES = (size_t)NBC * TOPK * NWORDS * 8;   // 18,432,000
    uint64_t* cand      = (uint64_t*)ws;                          // K3..K4
    uint64_t* gmask     = (uint64_t*)ws;                          // K5..K6 (overlay)
    uint32_t* ghist     = (uint32_t*)(ws + GMASK_BYTES);          // 147,456
    uint32_t* pivot     = (uint32_t*)(ws + GMASK_BYTES + 147456);
    uint32_t* gcnt      = (uint32_t*)(ws + GMASK_BYTES + 147456 + 576);
    float*    sel_box   = (float*)   (ws + GMASK_BYTES + 147456 + 1152);
    float*    sel_score = sel_box + (size_t)NBC * TOPK * 4;
    float*    final_sc  = sel_score + (size_t)NBC * TOPK;

    hipMemsetAsync(ghist, 0, (size_t)NBC * HBINS * 4, stream);

    score_hist_kernel<<<dim3(BATCH * BLK_PER_IMG), dim3(1024), 0, stream>>>(cls, obj, ghist);
    pivot_kernel<<<dim3(NBC), dim3(64), 0, stream>>>(ghist, pivot, gcnt);
    compact_kernel<<<dim3(BATCH * BLK_PER_IMG), dim3(1024), 0, stream>>>(cls, obj, pivot, gcnt, cand);
    sort_emit_kernel<<<dim3(NBC), dim3(1024), 0, stream>>>(cand, gcnt, anchors, deltas,
                                                           sel_box, sel_score);
    mask_build_kernel<<<dim3(NBC * NMS_SUB), dim3(1024), 0, stream>>>(sel_box, gmask);
    greedy_kernel<<<dim3(NBC), dim3(1024), 0, stream>>>(gmask, sel_score, final_sc);
    final_kernel<<<dim3(BATCH), dim3(1024), 0, stream>>>(final_sc, sel_box, out);
}